// Round 7
// baseline (295.031 us; speedup 1.0000x reference)
//
#include <hip/hip_runtime.h>
#include <math.h>

#define NN 50000
#define NE 800000

typedef __attribute__((ext_vector_type(8))) short short8;
typedef __attribute__((ext_vector_type(8))) unsigned short ushort8;
typedef __attribute__((ext_vector_type(4))) float f32x4;

// workspace layout (offsets in 4-byte words)
#define OFF_DEG    0          // float[NN] -> dinv (written by k_col)
#define OFF_CNT    50000      // int[NN]
#define OFF_ROWPTR 100000     // int[NN+1]
#define OFF_BSUM   200008     // int[64]
#define OFF_WB     200072     // ushort[256*384] = 49152 words
#define OFF_BIAS   249224     // float[256]
#define OFF_ELIST  249480     // uint[NE] (packed bf16norm<<16 | src)
#define OFF_XB     1849480    // ushort[NN*64] = 1.6M words each
#define OFF_HB     3449480
#define OFF_T1X    5049480
#define OFF_T1H    6649480
#define OFF_T2X    8249480
#define OFF_T2H    9849480
// overlays (consumed before T1/T2 are written by the props):
#define OFF_HISTP  5049480    // ushort[64][50000] partial dst-histograms
#define OFF_COLEXC 6649480    // ushort[64][50000] per-chunk exclusive offsets
#define OFF_DEGP   8249480    // float[64][50000] partial src-degrees

#define HCHUNK 12500          // edges per chunk (64 chunks)
#define HITER  49             // ceil(12500/256)

__device__ inline unsigned short f2bf(float f) {
  union { float f; unsigned u; } v; v.f = f;
  unsigned u = v.u;
  return (unsigned short)((u + 0x7FFFu + ((u >> 16) & 1u)) >> 16);
}
__device__ inline float bf2f(unsigned short u) {
  return __uint_as_float(((unsigned)u) << 16);
}
__device__ inline float sigm(float x) { return 1.f / (1.f + __expf(-x)); }
__device__ inline float tanh_(float x) { return 1.f - 2.f / (__expf(2.f * x) + 1.f); }

// fused LDS histogram (dst counts, packed 2x16b) + src degree partials (float)
__global__ __launch_bounds__(256) void k_hd(
    const int* __restrict__ src, const int* __restrict__ dst,
    const float* __restrict__ w,
    unsigned* __restrict__ histp, float* __restrict__ degp) {
  __shared__ unsigned lds[25000];  // 100 KB
  const int t = threadIdx.x;
  const int bid = blockIdx.x;
  if (bid < 64) {
    // dst histogram for chunk bid
    for (int i = t; i < 25000; i += 256) lds[i] = 0u;
    __syncthreads();
    const int e0 = bid * HCHUNK;
    for (int it = 0; it < HITER; ++it) {
      int o = it * 256 + t;
      if (o < HCHUNK) {
        int d = dst[e0 + o];
        atomicAdd(&lds[d >> 1], (d & 1) ? 65536u : 1u);
      }
    }
    __syncthreads();
    unsigned* hw = histp + bid * 25000;
    for (int i = t; i < 25000; i += 256) hw[i] = lds[i];
  } else {
    // src degree partials for chunk bid-64, two half-ranges of 25000 bins
    const int b2 = bid - 64;
    const int e0 = b2 * HCHUNK;
    float* ldsf = (float*)lds;
    for (int half = 0; half < 2; ++half) {
      __syncthreads();
      for (int i = t; i < 25000; i += 256) ldsf[i] = 0.f;
      __syncthreads();
      const int lo = half * 25000;
      for (int it = 0; it < HITER; ++it) {
        int o = it * 256 + t;
        if (o < HCHUNK) {
          int s = src[e0 + o];
          if ((unsigned)(s - lo) < 25000u) atomicAdd(&ldsf[s - lo], w[e0 + o]);
        }
      }
      __syncthreads();
      float* dw = degp + b2 * 50000 + lo;
      for (int i = t; i < 25000; i += 256) dw[i] = ldsf[i];
    }
  }
}

// cvt (X,H -> bf16, 8/thread) + wconv (weights -> bf16 Wb[col][kk], bias)
#define CBLK 1563
__global__ __launch_bounds__(256) void k_cw(
    const float* __restrict__ X, const float* __restrict__ H,
    unsigned short* __restrict__ Xb, unsigned short* __restrict__ Hb,
    const float* __restrict__ Wx, const float* __restrict__ Wh,
    const float* __restrict__ bx, const float* __restrict__ bh,
    const float* __restrict__ bg,
    unsigned short* __restrict__ Wb, float* __restrict__ bias) {
  const int bid = blockIdx.x;
  const int t = threadIdx.x;
  if (bid < CBLK) {
    int i = (bid * 256 + t) * 8;
    if (i >= NN * 64) return;
    float4 x0 = *(const float4*)&X[i];
    float4 x1 = *(const float4*)&X[i + 4];
    float4 h0 = *(const float4*)&H[i];
    float4 h1 = *(const float4*)&H[i + 4];
    ushort8 xb, hb;
    xb[0] = f2bf(x0.x); xb[1] = f2bf(x0.y); xb[2] = f2bf(x0.z); xb[3] = f2bf(x0.w);
    xb[4] = f2bf(x1.x); xb[5] = f2bf(x1.y); xb[6] = f2bf(x1.z); xb[7] = f2bf(x1.w);
    hb[0] = f2bf(h0.x); hb[1] = f2bf(h0.y); hb[2] = f2bf(h0.z); hb[3] = f2bf(h0.w);
    hb[4] = f2bf(h1.x); hb[5] = f2bf(h1.y); hb[6] = f2bf(h1.z); hb[7] = f2bf(h1.w);
    *(ushort8*)&Xb[i] = xb;
    *(ushort8*)&Hb[i] = hb;
  } else {
    int idx = (bid - CBLK) * 256 + t;
    if (idx < 256) bias[idx] = bx[idx] + bh[idx] + bg[idx];
    if (idx >= 256 * 384) return;
    int col = idx / 384;
    int kk = idx - col * 384;
    int g = col >> 6, cc = col & 63;
    int seg = kk >> 6, k = kk & 63;
    float v = (seg < 3) ? Wx[((g * 3 + seg) * 64 + k) * 64 + cc]
                        : Wh[((g * 3 + (seg - 3)) * 64 + k) * 64 + cc];
    Wb[idx] = f2bf(v);
  }
}

// per-bin column sums: cnt + colexc (prefix over chunks) + dinv
__global__ void k_col(const unsigned short* __restrict__ histp,
                      unsigned short* __restrict__ colexc,
                      const float* __restrict__ degp,
                      int* __restrict__ cnt, float* __restrict__ dinv) {
  int bin = blockIdx.x * 256 + threadIdx.x;
  if (bin >= NN) return;
  int acc = 0;
#pragma unroll 8
  for (int b = 0; b < 64; ++b) {
    unsigned short c = histp[b * 50000 + bin];
    colexc[b * 50000 + bin] = (unsigned short)acc;
    acc += c;
  }
  cnt[bin] = acc;
  float dacc = 0.f;
#pragma unroll 8
  for (int b = 0; b < 64; ++b) dacc += degp[b * 50000 + bin];
  dinv[bin] = (dacc > 0.f) ? rsqrtf(dacc) : 0.f;
}

// phase A: per-block (1024) local inclusive scan -> rowptr[i+1]; block sum -> bsum
__global__ __launch_bounds__(1024) void k_scanA(const int* __restrict__ cnt,
                                                int* __restrict__ rowptr,
                                                int* __restrict__ bsum) {
  __shared__ int wsum[16];
  int t = threadIdx.x, lane = t & 63, w = t >> 6;
  int i = blockIdx.x * 1024 + t;
  int v = (i < NN) ? cnt[i] : 0;
  int val = v;
#pragma unroll
  for (int off = 1; off < 64; off <<= 1) {
    int u = __shfl_up(val, off, 64);
    if (lane >= off) val += u;
  }
  if (lane == 63) wsum[w] = val;
  __syncthreads();
  if (w == 0) {
    int s = (lane < 16) ? wsum[lane] : 0;
#pragma unroll
    for (int off = 1; off < 16; off <<= 1) {
      int u = __shfl_up(s, off, 64);
      if (lane >= off) s += u;
    }
    if (lane < 16) wsum[lane] = s;
  }
  __syncthreads();
  int incl = ((w > 0) ? wsum[w - 1] : 0) + val;
  if (i < NN) rowptr[i + 1] = incl;
  if (t == 1023) bsum[blockIdx.x] = incl;
}

__global__ void k_scanB(int* __restrict__ bsum, int* __restrict__ rowptr, int nblk) {
  int lane = threadIdx.x;
  int v = (lane < nblk) ? bsum[lane] : 0;
  int val = v;
#pragma unroll
  for (int off = 1; off < 64; off <<= 1) {
    int u = __shfl_up(val, off, 64);
    if (lane >= off) val += u;
  }
  if (lane < nblk) bsum[lane] = val - v;  // exclusive
  if (lane == 0) rowptr[0] = 0;
}

__global__ __launch_bounds__(1024) void k_scanC(int* __restrict__ rowptr,
                                                const int* __restrict__ bsum) {
  int i = blockIdx.x * 1024 + threadIdx.x;
  if (i >= NN) return;
  rowptr[i + 1] += bsum[blockIdx.x];
}

// atomic-free (global) scatter: rank via LDS packed counters
__global__ __launch_bounds__(256) void k_scat(
    const int* __restrict__ src, const int* __restrict__ dst,
    const float* __restrict__ w, const float* __restrict__ dinv,
    const int* __restrict__ rowptr, const unsigned short* __restrict__ colexc,
    unsigned* __restrict__ elist) {
  __shared__ unsigned lds[25000];
  const int t = threadIdx.x, b = blockIdx.x;
  for (int i = t; i < 25000; i += 256) lds[i] = 0u;
  __syncthreads();
  const int e0 = b * HCHUNK;
  for (int it = 0; it < HITER; ++it) {
    int o = it * 256 + t;
    if (o < HCHUNK) {
      int e = e0 + o;
      int s = src[e], d = dst[e];
      float nm = -dinv[s] * w[e] * dinv[d];
      unsigned old = atomicAdd(&lds[d >> 1], (d & 1) ? 65536u : 1u);
      int rank = (d & 1) ? (int)(old >> 16) : (int)(old & 0xffffu);
      int pos = rowptr[d] + (int)colexc[b * 50000 + d] + rank;
      elist[pos] = (((unsigned)f2bf(nm)) << 16) | (unsigned)s;
    }
  }
}

// wave-per-node prop: 64 lanes = 64 channels, X and H together.
// mode=1: out = 2*acc - base (Chebyshev T2)
__global__ __launch_bounds__(256) void k_prop(
    const int* __restrict__ rowptr, const unsigned* __restrict__ elist,
    const unsigned short* __restrict__ inX, const unsigned short* __restrict__ inH,
    unsigned short* __restrict__ outX, unsigned short* __restrict__ outH,
    const unsigned short* __restrict__ baseX, const unsigned short* __restrict__ baseH,
    int mode) {
  int n = __builtin_amdgcn_readfirstlane(blockIdx.x * 4 + (threadIdx.x >> 6));
  int c = threadIdx.x & 63;
  if (n >= NN) return;
  int beg = rowptr[n], end = rowptr[n + 1];
  float ax = 0.f, ah = 0.f;
  int i = beg;
  for (; i + 3 < end; i += 4) {
    unsigned u0 = elist[i], u1 = elist[i + 1], u2 = elist[i + 2], u3 = elist[i + 3];
    int s0 = (int)(u0 & 0xffffu), s1 = (int)(u1 & 0xffffu);
    int s2 = (int)(u2 & 0xffffu), s3 = (int)(u3 & 0xffffu);
    float n0 = __uint_as_float(u0 & 0xffff0000u);
    float n1 = __uint_as_float(u1 & 0xffff0000u);
    float n2 = __uint_as_float(u2 & 0xffff0000u);
    float n3 = __uint_as_float(u3 & 0xffff0000u);
    float x0 = bf2f(inX[s0 * 64 + c]), h0 = bf2f(inH[s0 * 64 + c]);
    float x1 = bf2f(inX[s1 * 64 + c]), h1 = bf2f(inH[s1 * 64 + c]);
    float x2 = bf2f(inX[s2 * 64 + c]), h2 = bf2f(inH[s2 * 64 + c]);
    float x3 = bf2f(inX[s3 * 64 + c]), h3 = bf2f(inH[s3 * 64 + c]);
    ax += n0 * x0; ah += n0 * h0;
    ax += n1 * x1; ah += n1 * h1;
    ax += n2 * x2; ah += n2 * h2;
    ax += n3 * x3; ah += n3 * h3;
  }
  for (; i < end; ++i) {
    unsigned u0 = elist[i];
    int s0 = (int)(u0 & 0xffffu);
    float n0 = __uint_as_float(u0 & 0xffff0000u);
    ax += n0 * bf2f(inX[s0 * 64 + c]);
    ah += n0 * bf2f(inH[s0 * 64 + c]);
  }
  int o = n * 64 + c;
  if (mode) {
    outX[o] = f2bf(2.f * ax - bf2f(baseX[o]));
    outH[o] = f2bf(2.f * ah - bf2f(baseH[o]));
  } else {
    outX[o] = f2bf(ax);
    outH[o] = f2bf(ah);
  }
}

// MFMA gates: 256 thr / 4 waves; block = 32 rows; wave w = gate w
#define PSTR 264  // pre[] row stride (2-way banks, free)
__global__ __launch_bounds__(256, 4) void k_gates(
    const unsigned short* __restrict__ Xb, const unsigned short* __restrict__ Hb,
    const unsigned short* __restrict__ T1X, const unsigned short* __restrict__ T1H,
    const unsigned short* __restrict__ T2X, const unsigned short* __restrict__ T2H,
    const unsigned short* __restrict__ Wb, const float* __restrict__ C,
    const float* __restrict__ bias, const float* __restrict__ wc,
    float* __restrict__ out) {
  __shared__ float pre[32 * PSTR];  // 33792 B
  const int t = threadIdx.x;
  const int wv = t >> 6;         // gate
  const int l = t & 63;
  const int base = blockIdx.x * 32;
  const int lr = l & 15;
  const int lk = (l >> 4) * 8;

  f32x4 acc[2][4];
#pragma unroll
  for (int rb = 0; rb < 2; ++rb)
#pragma unroll
    for (int cf = 0; cf < 4; ++cf) acc[rb][cf] = (f32x4){0.f, 0.f, 0.f, 0.f};

  int r0 = base + lr, r1 = base + 16 + lr;
  int r0c = (r0 < NN) ? r0 : NN - 1;
  int r1c = (r1 < NN) ? r1 : NN - 1;

  const unsigned short* segp[6] = {Xb, T1X, T2X, Hb, T1H, T2H};
#pragma unroll
  for (int seg = 0; seg < 6; ++seg) {
    const unsigned short* sp = segp[seg];
#pragma unroll
    for (int h = 0; h < 2; ++h) {
      const int kc = seg * 2 + h;
      const int ko = h * 32 + lk;
      short8 a0 = *(const short8*)&sp[r0c * 64 + ko];
      short8 a1 = *(const short8*)&sp[r1c * 64 + ko];
#pragma unroll
      for (int cf = 0; cf < 4; ++cf) {
        short8 b = *(const short8*)&Wb[(wv * 64 + cf * 16 + lr) * 384 + kc * 32 + lk];
        acc[0][cf] = __builtin_amdgcn_mfma_f32_16x16x32_bf16(a0, b, acc[0][cf], 0, 0, 0);
        acc[1][cf] = __builtin_amdgcn_mfma_f32_16x16x32_bf16(a1, b, acc[1][cf], 0, 0, 0);
      }
    }
  }

  // exchange: pre[row][wv*64 + cf*16 + lr]
#pragma unroll
  for (int rb = 0; rb < 2; ++rb)
#pragma unroll
    for (int cf = 0; cf < 4; ++cf)
#pragma unroll
      for (int qq = 0; qq < 4; ++qq) {
        int row = rb * 16 + (l >> 4) * 4 + qq;
        pre[row * PSTR + wv * 64 + cf * 16 + lr] = acc[rb][cf][qq];
      }
  __syncthreads();

  // fused gate epilogue
  for (int i = t; i < 32 * 64; i += 256) {
    int m = i >> 6;
    int cc = i & 63;
    int n = base + m;
    if (n >= NN) continue;
    const float* pr = &pre[m * PSTR];
    float cv = C[n * 64 + cc];
    float pI = pr[cc]        + bias[cc]        + wc[cc] * cv;
    float pF = pr[64 + cc]   + bias[64 + cc]   + wc[64 + cc] * cv;
    float pT = pr[128 + cc]  + bias[128 + cc];
    float I = sigm(pI);
    float F = sigm(pF);
    float T = tanh_(pT);
    float Cn = F * cv + I * T;
    float pO = pr[192 + cc]  + bias[192 + cc]  + wc[128 + cc] * Cn;
    float O = sigm(pO);
    out[n * 64 + cc] = O * tanh_(Cn);
    out[NN * 64 + n * 64 + cc] = Cn;
  }
}

extern "C" void kernel_launch(void* const* d_in, const int* in_sizes, int n_in,
                              void* d_out, int out_size, void* d_ws, size_t ws_size,
                              hipStream_t stream) {
  const float* X  = (const float*)d_in[0];
  const int*   ei = (const int*)d_in[1];
  const float* ew = (const float*)d_in[2];
  const float* H  = (const float*)d_in[3];
  const float* C  = (const float*)d_in[4];
  const float* Wx = (const float*)d_in[5];
  const float* bx = (const float*)d_in[6];
  const float* Wh = (const float*)d_in[7];
  const float* bh = (const float*)d_in[8];
  const float* wc = (const float*)d_in[9];
  const float* bg = (const float*)d_in[10];
  float* out = (float*)d_out;
  float* ws = (float*)d_ws;

  const int* src = ei;
  const int* dst = ei + NE;
  float* dinv = ws + OFF_DEG;
  int* cnt = (int*)(ws + OFF_CNT);
  int* rowptr = (int*)(ws + OFF_ROWPTR);
  int* bsum = (int*)(ws + OFF_BSUM);
  unsigned short* Wb = (unsigned short*)(ws + OFF_WB);
  float* bias = ws + OFF_BIAS;
  unsigned* elist = (unsigned*)(ws + OFF_ELIST);
  unsigned* histp = (unsigned*)(ws + OFF_HISTP);
  unsigned short* colexc = (unsigned short*)(ws + OFF_COLEXC);
  float* degp = ws + OFF_DEGP;
  unsigned short* Xb  = (unsigned short*)(ws + OFF_XB);
  unsigned short* Hb  = (unsigned short*)(ws + OFF_HB);
  unsigned short* T1X = (unsigned short*)(ws + OFF_T1X);
  unsigned short* T1H = (unsigned short*)(ws + OFF_T1H);
  unsigned short* T2X = (unsigned short*)(ws + OFF_T2X);
  unsigned short* T2H = (unsigned short*)(ws + OFF_T2H);

  const int NBLK = (NN + 1023) / 1024;  // 49

  k_hd<<<128, 256, 0, stream>>>(src, dst, ew, histp, degp);
  k_cw<<<CBLK + 384, 256, 0, stream>>>(X, H, Xb, Hb, Wx, Wh, bx, bh, bg, Wb, bias);
  k_col<<<(NN + 255) / 256, 256, 0, stream>>>((const unsigned short*)histp, colexc,
                                              degp, cnt, dinv);
  k_scanA<<<NBLK, 1024, 0, stream>>>(cnt, rowptr, bsum);
  k_scanB<<<1, 64, 0, stream>>>(bsum, rowptr, NBLK);
  k_scanC<<<NBLK, 1024, 0, stream>>>(rowptr, bsum);
  k_scat<<<64, 256, 0, stream>>>(src, dst, ew, dinv, rowptr, colexc, elist);
  k_prop<<<NN / 4, 256, 0, stream>>>(rowptr, elist, Xb, Hb, T1X, T1H,
                                     nullptr, nullptr, 0);
  k_prop<<<NN / 4, 256, 0, stream>>>(rowptr, elist, T1X, T1H, T2X, T2H,
                                     Xb, Hb, 1);
  k_gates<<<(NN + 31) / 32, 256, 0, stream>>>(Xb, Hb, T1X, T1H, T2X, T2H,
                                              Wb, C, bias, wc, out);
}

// Round 8
// 270.506 us; speedup vs baseline: 1.0907x; 1.0907x over previous
//
#include <hip/hip_runtime.h>
#include <math.h>

#define NN 50000
#define NE 800000

typedef __attribute__((ext_vector_type(8))) short short8;
typedef __attribute__((ext_vector_type(8))) unsigned short ushort8;
typedef __attribute__((ext_vector_type(4))) float f32x4;

// workspace layout (offsets in 4-byte words)
#define OFF_DEG    0          // float[NN] -> dinv (written by k_col)
#define OFF_CNT    50000      // int[NN]
#define OFF_ROWPTR 100000     // int[NN+1]
#define OFF_BSUM   200008     // int[64]
#define OFF_WB     200072     // ushort[256*384] = 49152 words
#define OFF_BIAS   249224     // float[256]
#define OFF_ELIST  249480     // uint[NE] (packed bf16norm<<16 | src)
#define OFF_XB     1849480    // ushort[NN*64] = 1.6M words each
#define OFF_HB     3449480
#define OFF_T1X    5049480
#define OFF_T1H    6649480
#define OFF_T2X    8249480
#define OFF_T2H    9849480
// overlays (consumed before their hosts are written):
#define OFF_HISTP  5049480    // ushort[128][50000] over T1X+T1H (k_col reads, props write later)
#define OFF_COLEXC 8249480    // ushort[128][50000] over T2X+T2H (k_scat reads before prop2)
#define OFF_DEGP   1849480    // float[64][50000] over XB+HB (k_col reads BEFORE k_cw writes)

#define DCH    128            // dst chunks
#define DCHUNK 6250
#define DITER  25             // ceil(6250/256)
#define SCH    64             // src (deg) chunks
#define SCHUNK 12500
#define SITER  49

__device__ inline unsigned short f2bf(float f) {
  union { float f; unsigned u; } v; v.f = f;
  unsigned u = v.u;
  return (unsigned short)((u + 0x7FFFu + ((u >> 16) & 1u)) >> 16);
}
__device__ inline float bf2f(unsigned short u) {
  return __uint_as_float(((unsigned)u) << 16);
}
__device__ inline float sigm(float x) { return 1.f / (1.f + __expf(-x)); }
__device__ inline float tanh_(float x) { return 1.f - 2.f / (__expf(2.f * x) + 1.f); }

// fused LDS histogram (dst counts, packed 2x16b, 128 chunks) + src degree partials (64 chunks)
__global__ __launch_bounds__(256) void k_hd(
    const int* __restrict__ src, const int* __restrict__ dst,
    const float* __restrict__ w,
    unsigned* __restrict__ histp, float* __restrict__ degp) {
  __shared__ unsigned lds[25000];  // 100 KB
  const int t = threadIdx.x;
  const int bid = blockIdx.x;
  if (bid < DCH) {
    for (int i = t; i < 25000; i += 256) lds[i] = 0u;
    __syncthreads();
    const int e0 = bid * DCHUNK;
    for (int it = 0; it < DITER; ++it) {
      int o = it * 256 + t;
      if (o < DCHUNK) {
        int d = dst[e0 + o];
        atomicAdd(&lds[d >> 1], (d & 1) ? 65536u : 1u);
      }
    }
    __syncthreads();
    unsigned* hw = histp + bid * 25000;
    for (int i = t; i < 25000; i += 256) hw[i] = lds[i];
  } else {
    const int b2 = bid - DCH;
    const int e0 = b2 * SCHUNK;
    float* ldsf = (float*)lds;
    for (int half = 0; half < 2; ++half) {
      __syncthreads();
      for (int i = t; i < 25000; i += 256) ldsf[i] = 0.f;
      __syncthreads();
      const int lo = half * 25000;
      for (int it = 0; it < SITER; ++it) {
        int o = it * 256 + t;
        if (o < SCHUNK) {
          int s = src[e0 + o];
          if ((unsigned)(s - lo) < 25000u) atomicAdd(&ldsf[s - lo], w[e0 + o]);
        }
      }
      __syncthreads();
      float* dw = degp + b2 * 50000 + lo;
      for (int i = t; i < 25000; i += 256) dw[i] = ldsf[i];
    }
  }
}

// per-bin column sums: cnt + colexc (prefix over 128 chunks) + dinv
__global__ void k_col(const unsigned short* __restrict__ histp,
                      unsigned short* __restrict__ colexc,
                      const float* __restrict__ degp,
                      int* __restrict__ cnt, float* __restrict__ dinv) {
  int bin = blockIdx.x * 256 + threadIdx.x;
  if (bin >= NN) return;
  int acc = 0;
#pragma unroll 8
  for (int b = 0; b < DCH; ++b) {
    unsigned short c = histp[b * 50000 + bin];
    colexc[b * 50000 + bin] = (unsigned short)acc;
    acc += c;
  }
  cnt[bin] = acc;
  float dacc = 0.f;
#pragma unroll 8
  for (int b = 0; b < SCH; ++b) dacc += degp[b * 50000 + bin];
  dinv[bin] = (dacc > 0.f) ? rsqrtf(dacc) : 0.f;
}

// cvt (X,H -> bf16, 8/thread) + wconv (weights -> bf16 Wb[col][kk], bias)
#define CBLK 1563
__global__ __launch_bounds__(256) void k_cw(
    const float* __restrict__ X, const float* __restrict__ H,
    unsigned short* __restrict__ Xb, unsigned short* __restrict__ Hb,
    const float* __restrict__ Wx, const float* __restrict__ Wh,
    const float* __restrict__ bx, const float* __restrict__ bh,
    const float* __restrict__ bg,
    unsigned short* __restrict__ Wb, float* __restrict__ bias) {
  const int bid = blockIdx.x;
  const int t = threadIdx.x;
  if (bid < CBLK) {
    int i = (bid * 256 + t) * 8;
    if (i >= NN * 64) return;
    float4 x0 = *(const float4*)&X[i];
    float4 x1 = *(const float4*)&X[i + 4];
    float4 h0 = *(const float4*)&H[i];
    float4 h1 = *(const float4*)&H[i + 4];
    ushort8 xb, hb;
    xb[0] = f2bf(x0.x); xb[1] = f2bf(x0.y); xb[2] = f2bf(x0.z); xb[3] = f2bf(x0.w);
    xb[4] = f2bf(x1.x); xb[5] = f2bf(x1.y); xb[6] = f2bf(x1.z); xb[7] = f2bf(x1.w);
    hb[0] = f2bf(h0.x); hb[1] = f2bf(h0.y); hb[2] = f2bf(h0.z); hb[3] = f2bf(h0.w);
    hb[4] = f2bf(h1.x); hb[5] = f2bf(h1.y); hb[6] = f2bf(h1.z); hb[7] = f2bf(h1.w);
    *(ushort8*)&Xb[i] = xb;
    *(ushort8*)&Hb[i] = hb;
  } else {
    int idx = (bid - CBLK) * 256 + t;
    if (idx < 256) bias[idx] = bx[idx] + bh[idx] + bg[idx];
    if (idx >= 256 * 384) return;
    int col = idx / 384;
    int kk = idx - col * 384;
    int g = col >> 6, cc = col & 63;
    int seg = kk >> 6, k = kk & 63;
    float v = (seg < 3) ? Wx[((g * 3 + seg) * 64 + k) * 64 + cc]
                        : Wh[((g * 3 + (seg - 3)) * 64 + k) * 64 + cc];
    Wb[idx] = f2bf(v);
  }
}

// phase A: per-block (1024) local inclusive scan -> rowptr[i+1]; block sum -> bsum
__global__ __launch_bounds__(1024) void k_scanA(const int* __restrict__ cnt,
                                                int* __restrict__ rowptr,
                                                int* __restrict__ bsum) {
  __shared__ int wsum[16];
  int t = threadIdx.x, lane = t & 63, w = t >> 6;
  int i = blockIdx.x * 1024 + t;
  int v = (i < NN) ? cnt[i] : 0;
  int val = v;
#pragma unroll
  for (int off = 1; off < 64; off <<= 1) {
    int u = __shfl_up(val, off, 64);
    if (lane >= off) val += u;
  }
  if (lane == 63) wsum[w] = val;
  __syncthreads();
  if (w == 0) {
    int s = (lane < 16) ? wsum[lane] : 0;
#pragma unroll
    for (int off = 1; off < 16; off <<= 1) {
      int u = __shfl_up(s, off, 64);
      if (lane >= off) s += u;
    }
    if (lane < 16) wsum[lane] = s;
  }
  __syncthreads();
  int incl = ((w > 0) ? wsum[w - 1] : 0) + val;
  if (i < NN) rowptr[i + 1] = incl;
  if (t == 1023) bsum[blockIdx.x] = incl;
}

__global__ void k_scanB(int* __restrict__ bsum, int* __restrict__ rowptr, int nblk) {
  int lane = threadIdx.x;
  int v = (lane < nblk) ? bsum[lane] : 0;
  int val = v;
#pragma unroll
  for (int off = 1; off < 64; off <<= 1) {
    int u = __shfl_up(val, off, 64);
    if (lane >= off) val += u;
  }
  if (lane < nblk) bsum[lane] = val - v;  // exclusive
  if (lane == 0) rowptr[0] = 0;
}

__global__ __launch_bounds__(1024) void k_scanC(int* __restrict__ rowptr,
                                                const int* __restrict__ bsum) {
  int i = blockIdx.x * 1024 + threadIdx.x;
  if (i >= NN) return;
  rowptr[i + 1] += bsum[blockIdx.x];
}

// scatter with LDS-only rank counters (128 chunks)
__global__ __launch_bounds__(256) void k_scat(
    const int* __restrict__ src, const int* __restrict__ dst,
    const float* __restrict__ w, const float* __restrict__ dinv,
    const int* __restrict__ rowptr, const unsigned short* __restrict__ colexc,
    unsigned* __restrict__ elist) {
  __shared__ unsigned lds[25000];
  const int t = threadIdx.x, b = blockIdx.x;
  for (int i = t; i < 25000; i += 256) lds[i] = 0u;
  __syncthreads();
  const int e0 = b * DCHUNK;
  for (int it = 0; it < DITER; ++it) {
    int o = it * 256 + t;
    if (o < DCHUNK) {
      int e = e0 + o;
      int s = src[e], d = dst[e];
      float nm = -dinv[s] * w[e] * dinv[d];
      unsigned old = atomicAdd(&lds[d >> 1], (d & 1) ? 65536u : 1u);
      int rank = (d & 1) ? (int)(old >> 16) : (int)(old & 0xffffu);
      int pos = rowptr[d] + (int)colexc[b * 50000 + d] + rank;
      elist[pos] = (((unsigned)f2bf(nm)) << 16) | (unsigned)s;
    }
  }
}

// wave-per-node prop: 64 lanes = 64 channels, X and H together.
// mode=1: out = 2*acc - base (Chebyshev T2)
__global__ __launch_bounds__(256) void k_prop(
    const int* __restrict__ rowptr, const unsigned* __restrict__ elist,
    const unsigned short* __restrict__ inX, const unsigned short* __restrict__ inH,
    unsigned short* __restrict__ outX, unsigned short* __restrict__ outH,
    const unsigned short* __restrict__ baseX, const unsigned short* __restrict__ baseH,
    int mode) {
  int n = __builtin_amdgcn_readfirstlane(blockIdx.x * 4 + (threadIdx.x >> 6));
  int c = threadIdx.x & 63;
  if (n >= NN) return;
  int beg = rowptr[n], end = rowptr[n + 1];
  float ax = 0.f, ah = 0.f;
  int i = beg;
  for (; i + 3 < end; i += 4) {
    unsigned u0 = elist[i], u1 = elist[i + 1], u2 = elist[i + 2], u3 = elist[i + 3];
    int s0 = (int)(u0 & 0xffffu), s1 = (int)(u1 & 0xffffu);
    int s2 = (int)(u2 & 0xffffu), s3 = (int)(u3 & 0xffffu);
    float n0 = __uint_as_float(u0 & 0xffff0000u);
    float n1 = __uint_as_float(u1 & 0xffff0000u);
    float n2 = __uint_as_float(u2 & 0xffff0000u);
    float n3 = __uint_as_float(u3 & 0xffff0000u);
    float x0 = bf2f(inX[s0 * 64 + c]), h0 = bf2f(inH[s0 * 64 + c]);
    float x1 = bf2f(inX[s1 * 64 + c]), h1 = bf2f(inH[s1 * 64 + c]);
    float x2 = bf2f(inX[s2 * 64 + c]), h2 = bf2f(inH[s2 * 64 + c]);
    float x3 = bf2f(inX[s3 * 64 + c]), h3 = bf2f(inH[s3 * 64 + c]);
    ax += n0 * x0; ah += n0 * h0;
    ax += n1 * x1; ah += n1 * h1;
    ax += n2 * x2; ah += n2 * h2;
    ax += n3 * x3; ah += n3 * h3;
  }
  for (; i < end; ++i) {
    unsigned u0 = elist[i];
    int s0 = (int)(u0 & 0xffffu);
    float n0 = __uint_as_float(u0 & 0xffff0000u);
    ax += n0 * bf2f(inX[s0 * 64 + c]);
    ah += n0 * bf2f(inH[s0 * 64 + c]);
  }
  int o = n * 64 + c;
  if (mode) {
    outX[o] = f2bf(2.f * ax - bf2f(baseX[o]));
    outH[o] = f2bf(2.f * ah - bf2f(baseH[o]));
  } else {
    outX[o] = f2bf(ax);
    outH[o] = f2bf(ah);
  }
}

// MFMA gates v4: 512 thr / 8 waves; wave = (gate, col-half), B register-persistent.
// Grid-stride over 64-row tiles; A-loads contiguous; LDS exchange + fused epilogue.
#define PSTR 258          // 4*258 % 32 == 8 -> exchange writes conflict-free
#define GT_TILES ((NN + 63) / 64)   // 782
__global__ __launch_bounds__(512, 1) void k_gates(
    const unsigned short* __restrict__ Xb, const unsigned short* __restrict__ Hb,
    const unsigned short* __restrict__ T1X, const unsigned short* __restrict__ T1H,
    const unsigned short* __restrict__ T2X, const unsigned short* __restrict__ T2H,
    const unsigned short* __restrict__ Wb, const float* __restrict__ C,
    const float* __restrict__ bias, const float* __restrict__ wc,
    float* __restrict__ out) {
  __shared__ float pre[64 * PSTR];  // 66048 B
  const int t = threadIdx.x;
  const int wv = t >> 6;
  const int l = t & 63;
  const int g = wv >> 1, ch = wv & 1;
  const int colb = g * 64 + ch * 32;
  const int lr = l & 15;
  const int lk = (l >> 4) * 8;

  // persistent B: this wave's 32 cols x 384 k = 24 frags = 96 VGPR
  short8 Bf[2][12];
#pragma unroll
  for (int cf = 0; cf < 2; ++cf)
#pragma unroll
    for (int kc = 0; kc < 12; ++kc)
      Bf[cf][kc] = *(const short8*)&Wb[(colb + cf * 16 + lr) * 384 + kc * 32 + lk];

  const unsigned short* segp[6] = {Xb, T1X, T2X, Hb, T1H, T2H};

  for (int tile = blockIdx.x; tile < GT_TILES; tile += gridDim.x) {
    const int base = tile * 64;
    f32x4 acc[4][2];
#pragma unroll
    for (int rb = 0; rb < 4; ++rb) {
      acc[rb][0] = (f32x4){0.f, 0.f, 0.f, 0.f};
      acc[rb][1] = (f32x4){0.f, 0.f, 0.f, 0.f};
    }

#pragma unroll
    for (int rb = 0; rb < 4; ++rb) {
      int r = base + rb * 16 + lr;
      int rc = (r < NN) ? r : NN - 1;
      short8 Af[12];
#pragma unroll
      for (int seg = 0; seg < 6; ++seg)
#pragma unroll
        for (int h = 0; h < 2; ++h)
          Af[seg * 2 + h] = *(const short8*)&segp[seg][rc * 64 + h * 32 + lk];
#pragma unroll
      for (int kc = 0; kc < 12; ++kc) {
        acc[rb][0] = __builtin_amdgcn_mfma_f32_16x16x32_bf16(Af[kc], Bf[0][kc], acc[rb][0], 0, 0, 0);
        acc[rb][1] = __builtin_amdgcn_mfma_f32_16x16x32_bf16(Af[kc], Bf[1][kc], acc[rb][1], 0, 0, 0);
      }
    }

    __syncthreads();  // previous tile's epilogue readers done
#pragma unroll
    for (int rb = 0; rb < 4; ++rb)
#pragma unroll
      for (int cf = 0; cf < 2; ++cf)
#pragma unroll
        for (int qq = 0; qq < 4; ++qq) {
          int row = rb * 16 + (l >> 4) * 4 + qq;
          pre[row * PSTR + colb + cf * 16 + lr] = acc[rb][cf][qq];
        }
    __syncthreads();

    // fused gate epilogue: 64 rows x 64 ch, 8 per thread
#pragma unroll
    for (int it = 0; it < 8; ++it) {
      int i = it * 512 + t;
      int m = i >> 6;
      int cc = i & 63;
      int n = base + m;
      if (n >= NN) continue;
      const float* pr = &pre[m * PSTR];
      float cv = C[n * 64 + cc];
      float pI = pr[cc]       + bias[cc]       + wc[cc] * cv;
      float pF = pr[64 + cc]  + bias[64 + cc]  + wc[64 + cc] * cv;
      float pT = pr[128 + cc] + bias[128 + cc];
      float I = sigm(pI);
      float F = sigm(pF);
      float T = tanh_(pT);
      float Cn = F * cv + I * T;
      float pO = pr[192 + cc] + bias[192 + cc] + wc[128 + cc] * Cn;
      float O = sigm(pO);
      out[n * 64 + cc] = O * tanh_(Cn);
      out[NN * 64 + n * 64 + cc] = Cn;
    }
  }
}

extern "C" void kernel_launch(void* const* d_in, const int* in_sizes, int n_in,
                              void* d_out, int out_size, void* d_ws, size_t ws_size,
                              hipStream_t stream) {
  const float* X  = (const float*)d_in[0];
  const int*   ei = (const int*)d_in[1];
  const float* ew = (const float*)d_in[2];
  const float* H  = (const float*)d_in[3];
  const float* C  = (const float*)d_in[4];
  const float* Wx = (const float*)d_in[5];
  const float* bx = (const float*)d_in[6];
  const float* Wh = (const float*)d_in[7];
  const float* bh = (const float*)d_in[8];
  const float* wc = (const float*)d_in[9];
  const float* bg = (const float*)d_in[10];
  float* out = (float*)d_out;
  float* ws = (float*)d_ws;

  const int* src = ei;
  const int* dst = ei + NE;
  float* dinv = ws + OFF_DEG;
  int* cnt = (int*)(ws + OFF_CNT);
  int* rowptr = (int*)(ws + OFF_ROWPTR);
  int* bsum = (int*)(ws + OFF_BSUM);
  unsigned short* Wb = (unsigned short*)(ws + OFF_WB);
  float* bias = ws + OFF_BIAS;
  unsigned* elist = (unsigned*)(ws + OFF_ELIST);
  unsigned* histp = (unsigned*)(ws + OFF_HISTP);
  unsigned short* colexc = (unsigned short*)(ws + OFF_COLEXC);
  float* degp = ws + OFF_DEGP;
  unsigned short* Xb  = (unsigned short*)(ws + OFF_XB);
  unsigned short* Hb  = (unsigned short*)(ws + OFF_HB);
  unsigned short* T1X = (unsigned short*)(ws + OFF_T1X);
  unsigned short* T1H = (unsigned short*)(ws + OFF_T1H);
  unsigned short* T2X = (unsigned short*)(ws + OFF_T2X);
  unsigned short* T2H = (unsigned short*)(ws + OFF_T2H);

  const int NBLK = (NN + 1023) / 1024;  // 49

  k_hd<<<DCH + SCH, 256, 0, stream>>>(src, dst, ew, histp, degp);
  k_col<<<(NN + 255) / 256, 256, 0, stream>>>((const unsigned short*)histp, colexc,
                                              degp, cnt, dinv);
  k_cw<<<CBLK + 384, 256, 0, stream>>>(X, H, Xb, Hb, Wx, Wh, bx, bh, bg, Wb, bias);
  k_scanA<<<NBLK, 1024, 0, stream>>>(cnt, rowptr, bsum);
  k_scanB<<<1, 64, 0, stream>>>(bsum, rowptr, NBLK);
  k_scanC<<<NBLK, 1024, 0, stream>>>(rowptr, bsum);
  k_scat<<<DCH, 256, 0, stream>>>(src, dst, ew, dinv, rowptr, colexc, elist);
  k_prop<<<NN / 4, 256, 0, stream>>>(rowptr, elist, Xb, Hb, T1X, T1H,
                                     nullptr, nullptr, 0);
  k_prop<<<NN / 4, 256, 0, stream>>>(rowptr, elist, T1X, T1H, T2X, T2H,
                                     Xb, Hb, 1);
  k_gates<<<256, 512, 0, stream>>>(Xb, Hb, T1X, T1H, T2X, T2H,
                                   Wb, C, bias, wc, out);
}

// Round 9
// 262.203 us; speedup vs baseline: 1.1252x; 1.0317x over previous
//
#include <hip/hip_runtime.h>
#include <math.h>

#define NN 50000
#define NE 800000

typedef __attribute__((ext_vector_type(8))) short short8;
typedef __attribute__((ext_vector_type(8))) unsigned short ushort8;
typedef __attribute__((ext_vector_type(4))) float f32x4;

// workspace layout (offsets in 4-byte words)
#define OFF_DEG    0          // float[NN] -> dinv (written by k_col)
#define OFF_CNT    50000      // int[NN]
#define OFF_ROWPTR 100000     // int[NN+1]
#define OFF_BSUM   200008     // int[64]
#define OFF_WB     200072     // ushort[256*384] = 49152 words
#define OFF_BIAS   249224     // float[256]
#define OFF_ELIST  249480     // uint[NE] (packed bf16norm<<16 | src)
#define OFF_XB     1849480    // ushort[NN*64] = 1.6M words each
#define OFF_HB     3449480
#define OFF_T1X    5049480
#define OFF_T1H    6649480
#define OFF_T2X    8249480
#define OFF_T2H    9849480
// overlays (consumed before their hosts are written):
#define OFF_HISTP  5049480    // ushort[128][50000] over T1X+T1H
#define OFF_COLEXC 8249480    // ushort[128][50000] over T2X+T2H
#define OFF_DEGP   1849480    // float[64][50000] over XB+HB (consumed before k_cw)

#define DCH    128            // dst chunks
#define DCHUNK 6250
#define DITER  25
#define SCH    64             // src (deg) chunks
#define SCHUNK 12500
#define SITER  49

__device__ inline unsigned short f2bf(float f) {
  union { float f; unsigned u; } v; v.f = f;
  unsigned u = v.u;
  return (unsigned short)((u + 0x7FFFu + ((u >> 16) & 1u)) >> 16);
}
__device__ inline float bf2f(unsigned short u) {
  return __uint_as_float(((unsigned)u) << 16);
}
__device__ inline float sigm(float x) { return 1.f / (1.f + __expf(-x)); }
__device__ inline float tanh_(float x) { return 1.f - 2.f / (__expf(2.f * x) + 1.f); }

// fused LDS histogram (dst counts, packed 2x16b, 128 chunks) + src degree partials (64 chunks)
__global__ __launch_bounds__(256) void k_hd(
    const int* __restrict__ src, const int* __restrict__ dst,
    const float* __restrict__ w,
    unsigned* __restrict__ histp, float* __restrict__ degp) {
  __shared__ unsigned lds[25000];  // 100 KB
  const int t = threadIdx.x;
  const int bid = blockIdx.x;
  if (bid < DCH) {
    for (int i = t; i < 25000; i += 256) lds[i] = 0u;
    __syncthreads();
    const int e0 = bid * DCHUNK;
    for (int it = 0; it < DITER; ++it) {
      int o = it * 256 + t;
      if (o < DCHUNK) {
        int d = dst[e0 + o];
        atomicAdd(&lds[d >> 1], (d & 1) ? 65536u : 1u);
      }
    }
    __syncthreads();
    unsigned* hw = histp + bid * 25000;
    for (int i = t; i < 25000; i += 256) hw[i] = lds[i];
  } else {
    const int b2 = bid - DCH;
    const int e0 = b2 * SCHUNK;
    float* ldsf = (float*)lds;
    for (int half = 0; half < 2; ++half) {
      __syncthreads();
      for (int i = t; i < 25000; i += 256) ldsf[i] = 0.f;
      __syncthreads();
      const int lo = half * 25000;
      for (int it = 0; it < SITER; ++it) {
        int o = it * 256 + t;
        if (o < SCHUNK) {
          int s = src[e0 + o];
          if ((unsigned)(s - lo) < 25000u) atomicAdd(&ldsf[s - lo], w[e0 + o]);
        }
      }
      __syncthreads();
      float* dw = degp + b2 * 50000 + lo;
      for (int i = t; i < 25000; i += 256) dw[i] = ldsf[i];
    }
  }
}

// per-bin column sums: cnt + colexc (prefix over 128 chunks) + dinv
__global__ void k_col(const unsigned short* __restrict__ histp,
                      unsigned short* __restrict__ colexc,
                      const float* __restrict__ degp,
                      int* __restrict__ cnt, float* __restrict__ dinv) {
  int bin = blockIdx.x * 256 + threadIdx.x;
  if (bin >= NN) return;
  int acc = 0;
#pragma unroll 8
  for (int b = 0; b < DCH; ++b) {
    unsigned short c = histp[b * 50000 + bin];
    colexc[b * 50000 + bin] = (unsigned short)acc;
    acc += c;
  }
  cnt[bin] = acc;
  float dacc = 0.f;
#pragma unroll 8
  for (int b = 0; b < SCH; ++b) dacc += degp[b * 50000 + bin];
  dinv[bin] = (dacc > 0.f) ? rsqrtf(dacc) : 0.f;
}

// cvt (X,H -> bf16, 8/thread) + wconv (weights -> bf16 Wb[col][kk], bias)
#define CBLK 1563
__global__ __launch_bounds__(256) void k_cw(
    const float* __restrict__ X, const float* __restrict__ H,
    unsigned short* __restrict__ Xb, unsigned short* __restrict__ Hb,
    const float* __restrict__ Wx, const float* __restrict__ Wh,
    const float* __restrict__ bx, const float* __restrict__ bh,
    const float* __restrict__ bg,
    unsigned short* __restrict__ Wb, float* __restrict__ bias) {
  const int bid = blockIdx.x;
  const int t = threadIdx.x;
  if (bid < CBLK) {
    int i = (bid * 256 + t) * 8;
    if (i >= NN * 64) return;
    float4 x0 = *(const float4*)&X[i];
    float4 x1 = *(const float4*)&X[i + 4];
    float4 h0 = *(const float4*)&H[i];
    float4 h1 = *(const float4*)&H[i + 4];
    ushort8 xb, hb;
    xb[0] = f2bf(x0.x); xb[1] = f2bf(x0.y); xb[2] = f2bf(x0.z); xb[3] = f2bf(x0.w);
    xb[4] = f2bf(x1.x); xb[5] = f2bf(x1.y); xb[6] = f2bf(x1.z); xb[7] = f2bf(x1.w);
    hb[0] = f2bf(h0.x); hb[1] = f2bf(h0.y); hb[2] = f2bf(h0.z); hb[3] = f2bf(h0.w);
    hb[4] = f2bf(h1.x); hb[5] = f2bf(h1.y); hb[6] = f2bf(h1.z); hb[7] = f2bf(h1.w);
    *(ushort8*)&Xb[i] = xb;
    *(ushort8*)&Hb[i] = hb;
  } else {
    int idx = (bid - CBLK) * 256 + t;
    if (idx < 256) bias[idx] = bx[idx] + bh[idx] + bg[idx];
    if (idx >= 256 * 384) return;
    int col = idx / 384;
    int kk = idx - col * 384;
    int g = col >> 6, cc = col & 63;
    int seg = kk >> 6, k = kk & 63;
    float v = (seg < 3) ? Wx[((g * 3 + seg) * 64 + k) * 64 + cc]
                        : Wh[((g * 3 + (seg - 3)) * 64 + k) * 64 + cc];
    Wb[idx] = f2bf(v);
  }
}

// phase A: per-block (1024) local inclusive scan -> rowptr[i+1]; block sum -> bsum
__global__ __launch_bounds__(1024) void k_scanA(const int* __restrict__ cnt,
                                                int* __restrict__ rowptr,
                                                int* __restrict__ bsum) {
  __shared__ int wsum[16];
  int t = threadIdx.x, lane = t & 63, w = t >> 6;
  int i = blockIdx.x * 1024 + t;
  int v = (i < NN) ? cnt[i] : 0;
  int val = v;
#pragma unroll
  for (int off = 1; off < 64; off <<= 1) {
    int u = __shfl_up(val, off, 64);
    if (lane >= off) val += u;
  }
  if (lane == 63) wsum[w] = val;
  __syncthreads();
  if (w == 0) {
    int s = (lane < 16) ? wsum[lane] : 0;
#pragma unroll
    for (int off = 1; off < 16; off <<= 1) {
      int u = __shfl_up(s, off, 64);
      if (lane >= off) s += u;
    }
    if (lane < 16) wsum[lane] = s;
  }
  __syncthreads();
  int incl = ((w > 0) ? wsum[w - 1] : 0) + val;
  if (i < NN) rowptr[i + 1] = incl;
  if (t == 1023) bsum[blockIdx.x] = incl;
}

__global__ void k_scanB(int* __restrict__ bsum, int* __restrict__ rowptr, int nblk) {
  int lane = threadIdx.x;
  int v = (lane < nblk) ? bsum[lane] : 0;
  int val = v;
#pragma unroll
  for (int off = 1; off < 64; off <<= 1) {
    int u = __shfl_up(val, off, 64);
    if (lane >= off) val += u;
  }
  if (lane < nblk) bsum[lane] = val - v;  // exclusive
  if (lane == 0) rowptr[0] = 0;
}

__global__ __launch_bounds__(1024) void k_scanC(int* __restrict__ rowptr,
                                                const int* __restrict__ bsum) {
  int i = blockIdx.x * 1024 + threadIdx.x;
  if (i >= NN) return;
  rowptr[i + 1] += bsum[blockIdx.x];
}

// scatter with LDS-only rank counters (128 chunks)
__global__ __launch_bounds__(256) void k_scat(
    const int* __restrict__ src, const int* __restrict__ dst,
    const float* __restrict__ w, const float* __restrict__ dinv,
    const int* __restrict__ rowptr, const unsigned short* __restrict__ colexc,
    unsigned* __restrict__ elist) {
  __shared__ unsigned lds[25000];
  const int t = threadIdx.x, b = blockIdx.x;
  for (int i = t; i < 25000; i += 256) lds[i] = 0u;
  __syncthreads();
  const int e0 = b * DCHUNK;
  for (int it = 0; it < DITER; ++it) {
    int o = it * 256 + t;
    if (o < DCHUNK) {
      int e = e0 + o;
      int s = src[e], d = dst[e];
      float nm = -dinv[s] * w[e] * dinv[d];
      unsigned old = atomicAdd(&lds[d >> 1], (d & 1) ? 65536u : 1u);
      int rank = (d & 1) ? (int)(old >> 16) : (int)(old & 0xffffu);
      int pos = rowptr[d] + (int)colexc[b * 50000 + d] + rank;
      elist[pos] = (((unsigned)f2bf(nm)) << 16) | (unsigned)s;
    }
  }
}

// prop v3: wave per node; lane = (edge-slot es 0-7, ch-group cg 0-7).
// Each gather: ushort8 -> one instr moves 8 edges x 128B. Shuffle-reduce es.
__global__ __launch_bounds__(256) void k_prop(
    const int* __restrict__ rowptr, const unsigned* __restrict__ elist,
    const unsigned short* __restrict__ inX, const unsigned short* __restrict__ inH,
    unsigned short* __restrict__ outX, unsigned short* __restrict__ outH,
    const unsigned short* __restrict__ baseX, const unsigned short* __restrict__ baseH,
    int mode) {
  const int n = blockIdx.x * 4 + (threadIdx.x >> 6);
  const int l = threadIdx.x & 63;
  const int es = l >> 3;
  const int cg = l & 7;
  if (n >= NN) return;
  const int beg = rowptr[n], end = rowptr[n + 1];
  float ax[8], ah[8];
#pragma unroll
  for (int j = 0; j < 8; ++j) { ax[j] = 0.f; ah[j] = 0.f; }
  for (int i0 = beg; i0 < end; i0 += 8) {
    int ie = i0 + es;
    unsigned u = (ie < end) ? elist[ie] : 0u;   // u=0 -> s=0, nm=+0.0f
    int s = (int)(u & 0xffffu);
    float nm = __uint_as_float(u & 0xffff0000u);
    ushort8 xv = *(const ushort8*)&inX[s * 64 + cg * 8];
    ushort8 hv = *(const ushort8*)&inH[s * 64 + cg * 8];
#pragma unroll
    for (int j = 0; j < 8; ++j) {
      ax[j] += nm * bf2f(xv[j]);
      ah[j] += nm * bf2f(hv[j]);
    }
  }
  // reduce over es (lanes strided by 8 share cg)
#pragma unroll
  for (int mask = 8; mask <= 32; mask <<= 1) {
#pragma unroll
    for (int j = 0; j < 8; ++j) {
      ax[j] += __shfl_xor(ax[j], mask, 64);
      ah[j] += __shfl_xor(ah[j], mask, 64);
    }
  }
  if (es == 0) {
    const int o = n * 64 + cg * 8;
    ushort8 ox, oh;
    if (mode) {
      ushort8 bx8 = *(const ushort8*)&baseX[o];
      ushort8 bh8 = *(const ushort8*)&baseH[o];
#pragma unroll
      for (int j = 0; j < 8; ++j) {
        ox[j] = f2bf(2.f * ax[j] - bf2f(bx8[j]));
        oh[j] = f2bf(2.f * ah[j] - bf2f(bh8[j]));
      }
    } else {
#pragma unroll
      for (int j = 0; j < 8; ++j) { ox[j] = f2bf(ax[j]); oh[j] = f2bf(ah[j]); }
    }
    *(ushort8*)&outX[o] = ox;
    *(ushort8*)&outH[o] = oh;
  }
}

// MFMA gates v6: no LDS, no barriers. Block = 64 rows; wave w = 16-col group;
// each wave computes ALL 4 gates for its cols -> epilogue fully in registers.
__global__ __launch_bounds__(256, 3) void k_gates(
    const unsigned short* __restrict__ Xb, const unsigned short* __restrict__ Hb,
    const unsigned short* __restrict__ T1X, const unsigned short* __restrict__ T1H,
    const unsigned short* __restrict__ T2X, const unsigned short* __restrict__ T2H,
    const unsigned short* __restrict__ Wb, const float* __restrict__ C,
    const float* __restrict__ bias, const float* __restrict__ wc,
    float* __restrict__ out) {
  const int t = threadIdx.x;
  const int cw = t >> 6;        // col-group (16 cols within each gate)
  const int l = t & 63;
  const int base = blockIdx.x * 64;
  const int lr = l & 15;
  const int lk = (l >> 4) * 8;

  f32x4 acc[4][4];              // [gate][row-block]
#pragma unroll
  for (int g = 0; g < 4; ++g)
#pragma unroll
    for (int rb = 0; rb < 4; ++rb) acc[g][rb] = (f32x4){0.f, 0.f, 0.f, 0.f};

  int rc[4];
#pragma unroll
  for (int rb = 0; rb < 4; ++rb) {
    int r = base + rb * 16 + lr;
    rc[rb] = (r < NN) ? r : NN - 1;
  }

  const unsigned short* segp[6] = {Xb, T1X, T2X, Hb, T1H, T2H};
#pragma unroll
  for (int kc = 0; kc < 12; ++kc) {
    const unsigned short* sp = segp[kc >> 1];
    const int ko = (kc & 1) * 32 + lk;
    short8 a[4];
#pragma unroll
    for (int rb = 0; rb < 4; ++rb)
      a[rb] = *(const short8*)&sp[rc[rb] * 64 + ko];
#pragma unroll
    for (int g = 0; g < 4; ++g) {
      short8 b = *(const short8*)&Wb[(g * 64 + cw * 16 + lr) * 384 + kc * 32 + lk];
#pragma unroll
      for (int rb = 0; rb < 4; ++rb)
        acc[g][rb] = __builtin_amdgcn_mfma_f32_16x16x32_bf16(a[rb], b, acc[g][rb], 0, 0, 0);
    }
  }

  // epilogue in registers: lane holds col cc for rows rb*16 + (l>>4)*4 + q
  const int cc = cw * 16 + lr;
  const float bI = bias[cc],       bF = bias[64 + cc];
  const float bT = bias[128 + cc], bO = bias[192 + cc];
  const float wI = wc[cc], wF = wc[64 + cc], wO = wc[128 + cc];
#pragma unroll
  for (int rb = 0; rb < 4; ++rb) {
#pragma unroll
    for (int q = 0; q < 4; ++q) {
      int n = base + rb * 16 + (l >> 4) * 4 + q;
      if (n >= NN) continue;
      float cv = C[n * 64 + cc];
      float pI = acc[0][rb][q] + bI + wI * cv;
      float pF = acc[1][rb][q] + bF + wF * cv;
      float pT = acc[2][rb][q] + bT;
      float I = sigm(pI);
      float F = sigm(pF);
      float T = tanh_(pT);
      float Cn = F * cv + I * T;
      float pO = acc[3][rb][q] + bO + wO * Cn;
      float O = sigm(pO);
      out[n * 64 + cc] = O * tanh_(Cn);
      out[NN * 64 + n * 64 + cc] = Cn;
    }
  }
}

extern "C" void kernel_launch(void* const* d_in, const int* in_sizes, int n_in,
                              void* d_out, int out_size, void* d_ws, size_t ws_size,
                              hipStream_t stream) {
  const float* X  = (const float*)d_in[0];
  const int*   ei = (const int*)d_in[1];
  const float* ew = (const float*)d_in[2];
  const float* H  = (const float*)d_in[3];
  const float* C  = (const float*)d_in[4];
  const float* Wx = (const float*)d_in[5];
  const float* bx = (const float*)d_in[6];
  const float* Wh = (const float*)d_in[7];
  const float* bh = (const float*)d_in[8];
  const float* wc = (const float*)d_in[9];
  const float* bg = (const float*)d_in[10];
  float* out = (float*)d_out;
  float* ws = (float*)d_ws;

  const int* src = ei;
  const int* dst = ei + NE;
  float* dinv = ws + OFF_DEG;
  int* cnt = (int*)(ws + OFF_CNT);
  int* rowptr = (int*)(ws + OFF_ROWPTR);
  int* bsum = (int*)(ws + OFF_BSUM);
  unsigned short* Wb = (unsigned short*)(ws + OFF_WB);
  float* bias = ws + OFF_BIAS;
  unsigned* elist = (unsigned*)(ws + OFF_ELIST);
  unsigned* histp = (unsigned*)(ws + OFF_HISTP);
  unsigned short* colexc = (unsigned short*)(ws + OFF_COLEXC);
  float* degp = ws + OFF_DEGP;
  unsigned short* Xb  = (unsigned short*)(ws + OFF_XB);
  unsigned short* Hb  = (unsigned short*)(ws + OFF_HB);
  unsigned short* T1X = (unsigned short*)(ws + OFF_T1X);
  unsigned short* T1H = (unsigned short*)(ws + OFF_T1H);
  unsigned short* T2X = (unsigned short*)(ws + OFF_T2X);
  unsigned short* T2H = (unsigned short*)(ws + OFF_T2H);

  const int NBLK = (NN + 1023) / 1024;  // 49

  k_hd<<<DCH + SCH, 256, 0, stream>>>(src, dst, ew, histp, degp);
  k_col<<<(NN + 255) / 256, 256, 0, stream>>>((const unsigned short*)histp, colexc,
                                              degp, cnt, dinv);
  k_cw<<<CBLK + 384, 256, 0, stream>>>(X, H, Xb, Hb, Wx, Wh, bx, bh, bg, Wb, bias);
  k_scanA<<<NBLK, 1024, 0, stream>>>(cnt, rowptr, bsum);
  k_scanB<<<1, 64, 0, stream>>>(bsum, rowptr, NBLK);
  k_scanC<<<NBLK, 1024, 0, stream>>>(rowptr, bsum);
  k_scat<<<DCH, 256, 0, stream>>>(src, dst, ew, dinv, rowptr, colexc, elist);
  k_prop<<<NN / 4, 256, 0, stream>>>(rowptr, elist, Xb, Hb, T1X, T1H,
                                     nullptr, nullptr, 0);
  k_prop<<<NN / 4, 256, 0, stream>>>(rowptr, elist, T1X, T1H, T2X, T2H,
                                     Xb, Hb, 1);
  k_gates<<<(NN + 63) / 64, 256, 0, stream>>>(Xb, Hb, T1X, T1H, T2X, T2H,
                                              Wb, C, bias, wc, out);
}

// Round 10
// 247.844 us; speedup vs baseline: 1.1904x; 1.0579x over previous
//
#include <hip/hip_runtime.h>
#include <math.h>

#define NN 50000
#define NE 800000

typedef __attribute__((ext_vector_type(8))) short short8;
typedef __attribute__((ext_vector_type(8))) unsigned short ushort8;
typedef __attribute__((ext_vector_type(4))) float f32x4;

// workspace layout (offsets in 4-byte words)
#define OFF_DEG    0          // float[NN] -> dinv (written by k_col)
#define OFF_CNT    50000      // int[NN]
#define OFF_ROWPTR 100000     // int[NN+1]
#define OFF_BSUM   200008     // int[64]
#define OFF_WB     200072     // ushort[256*384] = 49152 words
#define OFF_BIAS   249224     // float[256]
#define OFF_ELIST  249480     // uint[NE] (packed bf16norm<<16 | src)
#define OFF_XB     1849480    // ushort[NN*64] = 1.6M words each
#define OFF_HB     3449480
#define OFF_T1X    5049480
#define OFF_T1H    6649480
#define OFF_T2X    8249480
#define OFF_T2H    9849480
// overlays (consumed before their hosts are written):
#define OFF_HISTP  5049480    // ushort[128][50000] over T1X+T1H
#define OFF_COLEXC 8249480    // ushort[128][50000] over T2X+T2H
#define OFF_DEGP   1849480    // float[64][50000] over XB+HB (consumed before k_cw)

#define DCH    128            // dst chunks
#define DCHUNK 6250
#define DITER  25
#define SCH    64             // src (deg) chunks
#define SCHUNK 12500
#define SITER  49

__device__ inline unsigned short f2bf(float f) {
  union { float f; unsigned u; } v; v.f = f;
  unsigned u = v.u;
  return (unsigned short)((u + 0x7FFFu + ((u >> 16) & 1u)) >> 16);
}
__device__ inline float bf2f(unsigned short u) {
  return __uint_as_float(((unsigned)u) << 16);
}
__device__ inline float sigm(float x) { return 1.f / (1.f + __expf(-x)); }
__device__ inline float tanh_(float x) { return 1.f - 2.f / (__expf(2.f * x) + 1.f); }

// fused histogram/degree, 512 blocks @ 50KB LDS (3 blocks/CU):
//  bid<256: dst-hist, (chunk c = bid>>1) x (bin-half = bid&1), packed 2x16b
//  bid>=256: src-deg, (chunk c = idx>>2) x (bin-quarter = idx&3), float bins
__global__ __launch_bounds__(256) void k_hd(
    const int* __restrict__ src, const int* __restrict__ dst,
    const float* __restrict__ w,
    unsigned short* __restrict__ histp, float* __restrict__ degp) {
  __shared__ unsigned lds[12500];  // 50 KB
  const int t = threadIdx.x;
  const int bid = blockIdx.x;
  if (bid < 256) {
    const int c = bid >> 1, half = bid & 1, lo = half * 25000;
    for (int i = t; i < 12500; i += 256) lds[i] = 0u;
    __syncthreads();
    const int e0 = c * DCHUNK;
    for (int it = 0; it < DITER; ++it) {
      int o = it * 256 + t;
      if (o < DCHUNK) {
        int d = dst[e0 + o] - lo;
        if ((unsigned)d < 25000u)
          atomicAdd(&lds[d >> 1], (d & 1) ? 65536u : 1u);
      }
    }
    __syncthreads();
    unsigned* hw = (unsigned*)(histp + c * 50000 + lo);
    for (int i = t; i < 12500; i += 256) hw[i] = lds[i];
  } else {
    const int idx = bid - 256;
    const int c = idx >> 2, q = idx & 3, lo = q * 12500;
    float* ldsf = (float*)lds;
    for (int i = t; i < 12500; i += 256) ldsf[i] = 0.f;
    __syncthreads();
    const int e0 = c * SCHUNK;
    for (int it = 0; it < SITER; ++it) {
      int o = it * 256 + t;
      if (o < SCHUNK) {
        int s = src[e0 + o] - lo;
        if ((unsigned)s < 12500u) atomicAdd(&ldsf[s], w[e0 + o]);
      }
    }
    __syncthreads();
    float* dw = degp + c * 50000 + lo;
    for (int i = t; i < 12500; i += 256) dw[i] = ldsf[i];
  }
}

// per-bin column sums: cnt + colexc (prefix over 128 chunks) + dinv
__global__ void k_col(const unsigned short* __restrict__ histp,
                      unsigned short* __restrict__ colexc,
                      const float* __restrict__ degp,
                      int* __restrict__ cnt, float* __restrict__ dinv) {
  int bin = blockIdx.x * 256 + threadIdx.x;
  if (bin >= NN) return;
  int acc = 0;
#pragma unroll 8
  for (int b = 0; b < DCH; ++b) {
    unsigned short c = histp[b * 50000 + bin];
    colexc[b * 50000 + bin] = (unsigned short)acc;
    acc += c;
  }
  cnt[bin] = acc;
  float dacc = 0.f;
#pragma unroll 8
  for (int b = 0; b < SCH; ++b) dacc += degp[b * 50000 + bin];
  dinv[bin] = (dacc > 0.f) ? rsqrtf(dacc) : 0.f;
}

// cvt (X,H -> bf16, 8/thread) + wconv (weights -> bf16 Wb[col][kk], bias)
#define CBLK 1563
__global__ __launch_bounds__(256) void k_cw(
    const float* __restrict__ X, const float* __restrict__ H,
    unsigned short* __restrict__ Xb, unsigned short* __restrict__ Hb,
    const float* __restrict__ Wx, const float* __restrict__ Wh,
    const float* __restrict__ bx, const float* __restrict__ bh,
    const float* __restrict__ bg,
    unsigned short* __restrict__ Wb, float* __restrict__ bias) {
  const int bid = blockIdx.x;
  const int t = threadIdx.x;
  if (bid < CBLK) {
    int i = (bid * 256 + t) * 8;
    if (i >= NN * 64) return;
    float4 x0 = *(const float4*)&X[i];
    float4 x1 = *(const float4*)&X[i + 4];
    float4 h0 = *(const float4*)&H[i];
    float4 h1 = *(const float4*)&H[i + 4];
    ushort8 xb, hb;
    xb[0] = f2bf(x0.x); xb[1] = f2bf(x0.y); xb[2] = f2bf(x0.z); xb[3] = f2bf(x0.w);
    xb[4] = f2bf(x1.x); xb[5] = f2bf(x1.y); xb[6] = f2bf(x1.z); xb[7] = f2bf(x1.w);
    hb[0] = f2bf(h0.x); hb[1] = f2bf(h0.y); hb[2] = f2bf(h0.z); hb[3] = f2bf(h0.w);
    hb[4] = f2bf(h1.x); hb[5] = f2bf(h1.y); hb[6] = f2bf(h1.z); hb[7] = f2bf(h1.w);
    *(ushort8*)&Xb[i] = xb;
    *(ushort8*)&Hb[i] = hb;
  } else {
    int idx = (bid - CBLK) * 256 + t;
    if (idx < 256) bias[idx] = bx[idx] + bh[idx] + bg[idx];
    if (idx >= 256 * 384) return;
    int col = idx / 384;
    int kk = idx - col * 384;
    int g = col >> 6, cc = col & 63;
    int seg = kk >> 6, k = kk & 63;
    float v = (seg < 3) ? Wx[((g * 3 + seg) * 64 + k) * 64 + cc]
                        : Wh[((g * 3 + (seg - 3)) * 64 + k) * 64 + cc];
    Wb[idx] = f2bf(v);
  }
}

// phase A: per-block (1024) local inclusive scan -> rowptr[i+1]; block sum -> bsum
__global__ __launch_bounds__(1024) void k_scanA(const int* __restrict__ cnt,
                                                int* __restrict__ rowptr,
                                                int* __restrict__ bsum) {
  __shared__ int wsum[16];
  int t = threadIdx.x, lane = t & 63, w = t >> 6;
  int i = blockIdx.x * 1024 + t;
  int v = (i < NN) ? cnt[i] : 0;
  int val = v;
#pragma unroll
  for (int off = 1; off < 64; off <<= 1) {
    int u = __shfl_up(val, off, 64);
    if (lane >= off) val += u;
  }
  if (lane == 63) wsum[w] = val;
  __syncthreads();
  if (w == 0) {
    int s = (lane < 16) ? wsum[lane] : 0;
#pragma unroll
    for (int off = 1; off < 16; off <<= 1) {
      int u = __shfl_up(s, off, 64);
      if (lane >= off) s += u;
    }
    if (lane < 16) wsum[lane] = s;
  }
  __syncthreads();
  int incl = ((w > 0) ? wsum[w - 1] : 0) + val;
  if (i < NN) rowptr[i + 1] = incl;
  if (t == 1023) bsum[blockIdx.x] = incl;
}

__global__ void k_scanB(int* __restrict__ bsum, int* __restrict__ rowptr, int nblk) {
  int lane = threadIdx.x;
  int v = (lane < nblk) ? bsum[lane] : 0;
  int val = v;
#pragma unroll
  for (int off = 1; off < 64; off <<= 1) {
    int u = __shfl_up(val, off, 64);
    if (lane >= off) val += u;
  }
  if (lane < nblk) bsum[lane] = val - v;  // exclusive
  if (lane == 0) rowptr[0] = 0;
}

__global__ __launch_bounds__(1024) void k_scanC(int* __restrict__ rowptr,
                                                const int* __restrict__ bsum) {
  int i = blockIdx.x * 1024 + threadIdx.x;
  if (i >= NN) return;
  rowptr[i + 1] += bsum[blockIdx.x];
}

// scatter, 256 blocks @ 50KB: (chunk c = bid>>1) x (bin-half = bid&1)
__global__ __launch_bounds__(256) void k_scat(
    const int* __restrict__ src, const int* __restrict__ dst,
    const float* __restrict__ w, const float* __restrict__ dinv,
    const int* __restrict__ rowptr, const unsigned short* __restrict__ colexc,
    unsigned* __restrict__ elist) {
  __shared__ unsigned lds[12500];
  const int t = threadIdx.x, bid = blockIdx.x;
  const int c = bid >> 1, half = bid & 1, lo = half * 25000;
  for (int i = t; i < 12500; i += 256) lds[i] = 0u;
  __syncthreads();
  const int e0 = c * DCHUNK;
  for (int it = 0; it < DITER; ++it) {
    int o = it * 256 + t;
    if (o < DCHUNK) {
      int e = e0 + o;
      int d = dst[e];
      int dr = d - lo;
      if ((unsigned)dr < 25000u) {
        int s = src[e];
        float nm = -dinv[s] * w[e] * dinv[d];
        unsigned old = atomicAdd(&lds[dr >> 1], (dr & 1) ? 65536u : 1u);
        int rank = (dr & 1) ? (int)(old >> 16) : (int)(old & 0xffffu);
        int pos = rowptr[d] + (int)colexc[c * 50000 + d] + rank;
        elist[pos] = (((unsigned)f2bf(nm)) << 16) | (unsigned)s;
      }
    }
  }
}

// prop v3: wave per node; lane = (edge-slot es 0-7, ch-group cg 0-7).
__global__ __launch_bounds__(256) void k_prop(
    const int* __restrict__ rowptr, const unsigned* __restrict__ elist,
    const unsigned short* __restrict__ inX, const unsigned short* __restrict__ inH,
    unsigned short* __restrict__ outX, unsigned short* __restrict__ outH,
    const unsigned short* __restrict__ baseX, const unsigned short* __restrict__ baseH,
    int mode) {
  const int n = blockIdx.x * 4 + (threadIdx.x >> 6);
  const int l = threadIdx.x & 63;
  const int es = l >> 3;
  const int cg = l & 7;
  if (n >= NN) return;
  const int beg = rowptr[n], end = rowptr[n + 1];
  float ax[8], ah[8];
#pragma unroll
  for (int j = 0; j < 8; ++j) { ax[j] = 0.f; ah[j] = 0.f; }
  for (int i0 = beg; i0 < end; i0 += 8) {
    int ie = i0 + es;
    unsigned u = (ie < end) ? elist[ie] : 0u;   // u=0 -> s=0, nm=+0.0f
    int s = (int)(u & 0xffffu);
    float nm = __uint_as_float(u & 0xffff0000u);
    ushort8 xv = *(const ushort8*)&inX[s * 64 + cg * 8];
    ushort8 hv = *(const ushort8*)&inH[s * 64 + cg * 8];
#pragma unroll
    for (int j = 0; j < 8; ++j) {
      ax[j] += nm * bf2f(xv[j]);
      ah[j] += nm * bf2f(hv[j]);
    }
  }
#pragma unroll
  for (int mask = 8; mask <= 32; mask <<= 1) {
#pragma unroll
    for (int j = 0; j < 8; ++j) {
      ax[j] += __shfl_xor(ax[j], mask, 64);
      ah[j] += __shfl_xor(ah[j], mask, 64);
    }
  }
  if (es == 0) {
    const int o = n * 64 + cg * 8;
    ushort8 ox, oh;
    if (mode) {
      ushort8 bx8 = *(const ushort8*)&baseX[o];
      ushort8 bh8 = *(const ushort8*)&baseH[o];
#pragma unroll
      for (int j = 0; j < 8; ++j) {
        ox[j] = f2bf(2.f * ax[j] - bf2f(bx8[j]));
        oh[j] = f2bf(2.f * ah[j] - bf2f(bh8[j]));
      }
    } else {
#pragma unroll
      for (int j = 0; j < 8; ++j) { ox[j] = f2bf(ax[j]); oh[j] = f2bf(ah[j]); }
    }
    *(ushort8*)&outX[o] = ox;
    *(ushort8*)&outH[o] = oh;
  }
}

// MFMA gates v7: no LDS/barriers; block = 32 rows (1563 blocks), wave = 16-col
// group computing all 4 gates; acc = 32 VGPR -> load-pipelining headroom.
__global__ __launch_bounds__(256, 4) void k_gates(
    const unsigned short* __restrict__ Xb, const unsigned short* __restrict__ Hb,
    const unsigned short* __restrict__ T1X, const unsigned short* __restrict__ T1H,
    const unsigned short* __restrict__ T2X, const unsigned short* __restrict__ T2H,
    const unsigned short* __restrict__ Wb, const float* __restrict__ C,
    const float* __restrict__ bias, const float* __restrict__ wc,
    float* __restrict__ out) {
  const int t = threadIdx.x;
  const int cw = t >> 6;        // col-group (16 cols within each gate)
  const int l = t & 63;
  const int base = blockIdx.x * 32;
  const int lr = l & 15;
  const int lk = (l >> 4) * 8;

  f32x4 acc[4][2];              // [gate][row-block]
#pragma unroll
  for (int g = 0; g < 4; ++g)
#pragma unroll
    for (int rb = 0; rb < 2; ++rb) acc[g][rb] = (f32x4){0.f, 0.f, 0.f, 0.f};

  int rc[2];
#pragma unroll
  for (int rb = 0; rb < 2; ++rb) {
    int r = base + rb * 16 + lr;
    rc[rb] = (r < NN) ? r : NN - 1;
  }

  const unsigned short* segp[6] = {Xb, T1X, T2X, Hb, T1H, T2H};
#pragma unroll
  for (int kc = 0; kc < 12; ++kc) {
    const unsigned short* sp = segp[kc >> 1];
    const int ko = (kc & 1) * 32 + lk;
    short8 a[2];
#pragma unroll
    for (int rb = 0; rb < 2; ++rb)
      a[rb] = *(const short8*)&sp[rc[rb] * 64 + ko];
#pragma unroll
    for (int g = 0; g < 4; ++g) {
      short8 b = *(const short8*)&Wb[(g * 64 + cw * 16 + lr) * 384 + kc * 32 + lk];
#pragma unroll
      for (int rb = 0; rb < 2; ++rb)
        acc[g][rb] = __builtin_amdgcn_mfma_f32_16x16x32_bf16(a[rb], b, acc[g][rb], 0, 0, 0);
    }
  }

  const int cc = cw * 16 + lr;
  const float bI = bias[cc],       bF = bias[64 + cc];
  const float bT = bias[128 + cc], bO = bias[192 + cc];
  const float wI = wc[cc], wF = wc[64 + cc], wO = wc[128 + cc];
#pragma unroll
  for (int rb = 0; rb < 2; ++rb) {
#pragma unroll
    for (int q = 0; q < 4; ++q) {
      int n = base + rb * 16 + (l >> 4) * 4 + q;
      if (n >= NN) continue;
      float cv = C[n * 64 + cc];
      float pI = acc[0][rb][q] + bI + wI * cv;
      float pF = acc[1][rb][q] + bF + wF * cv;
      float pT = acc[2][rb][q] + bT;
      float I = sigm(pI);
      float F = sigm(pF);
      float T = tanh_(pT);
      float Cn = F * cv + I * T;
      float pO = acc[3][rb][q] + bO + wO * Cn;
      float O = sigm(pO);
      out[n * 64 + cc] = O * tanh_(Cn);
      out[NN * 64 + n * 64 + cc] = Cn;
    }
  }
}

extern "C" void kernel_launch(void* const* d_in, const int* in_sizes, int n_in,
                              void* d_out, int out_size, void* d_ws, size_t ws_size,
                              hipStream_t stream) {
  const float* X  = (const float*)d_in[0];
  const int*   ei = (const int*)d_in[1];
  const float* ew = (const float*)d_in[2];
  const float* H  = (const float*)d_in[3];
  const float* C  = (const float*)d_in[4];
  const float* Wx = (const float*)d_in[5];
  const float* bx = (const float*)d_in[6];
  const float* Wh = (const float*)d_in[7];
  const float* bh = (const float*)d_in[8];
  const float* wc = (const float*)d_in[9];
  const float* bg = (const float*)d_in[10];
  float* out = (float*)d_out;
  float* ws = (float*)d_ws;

  const int* src = ei;
  const int* dst = ei + NE;
  float* dinv = ws + OFF_DEG;
  int* cnt = (int*)(ws + OFF_CNT);
  int* rowptr = (int*)(ws + OFF_ROWPTR);
  int* bsum = (int*)(ws + OFF_BSUM);
  unsigned short* Wb = (unsigned short*)(ws + OFF_WB);
  float* bias = ws + OFF_BIAS;
  unsigned* elist = (unsigned*)(ws + OFF_ELIST);
  unsigned short* histp = (unsigned short*)(ws + OFF_HISTP);
  unsigned short* colexc = (unsigned short*)(ws + OFF_COLEXC);
  float* degp = ws + OFF_DEGP;
  unsigned short* Xb  = (unsigned short*)(ws + OFF_XB);
  unsigned short* Hb  = (unsigned short*)(ws + OFF_HB);
  unsigned short* T1X = (unsigned short*)(ws + OFF_T1X);
  unsigned short* T1H = (unsigned short*)(ws + OFF_T1H);
  unsigned short* T2X = (unsigned short*)(ws + OFF_T2X);
  unsigned short* T2H = (unsigned short*)(ws + OFF_T2H);

  const int NBLK = (NN + 1023) / 1024;  // 49

  k_hd<<<512, 256, 0, stream>>>(src, dst, ew, histp, degp);
  k_col<<<(NN + 255) / 256, 256, 0, stream>>>(histp, colexc, degp, cnt, dinv);
  k_cw<<<CBLK + 384, 256, 0, stream>>>(X, H, Xb, Hb, Wx, Wh, bx, bh, bg, Wb, bias);
  k_scanA<<<NBLK, 1024, 0, stream>>>(cnt, rowptr, bsum);
  k_scanB<<<1, 64, 0, stream>>>(bsum, rowptr, NBLK);
  k_scanC<<<NBLK, 1024, 0, stream>>>(rowptr, bsum);
  k_scat<<<256, 256, 0, stream>>>(src, dst, ew, dinv, rowptr, colexc, elist);
  k_prop<<<NN / 4, 256, 0, stream>>>(rowptr, elist, Xb, Hb, T1X, T1H,
                                     nullptr, nullptr, 0);
  k_prop<<<NN / 4, 256, 0, stream>>>(rowptr, elist, T1X, T1H, T2X, T2H,
                                     Xb, Hb, 1);
  k_gates<<<(NN + 31) / 32, 256, 0, stream>>>(Xb, Hb, T1X, T1H, T2X, T2H,
                                              Wb, C, bias, wc, out);
}